// Round 1
// baseline (585.424 us; speedup 1.0000x reference)
//
#include <hip/hip_runtime.h>

#define TPB 256

// Pack [total][3] float points into float4 {x, y, z, x^2+y^2+z^2}.
__global__ void __launch_bounds__(256) pack_pts(const float* __restrict__ pts,
                                                float4* __restrict__ out, int total) {
    int i = blockIdx.x * blockDim.x + threadIdx.x;
    if (i < total) {
        float x = pts[3 * i + 0];
        float y = pts[3 * i + 1];
        float z = pts[3 * i + 2];
        out[i] = make_float4(x, y, z, fmaf(x, x, fmaf(y, y, z * z)));
    }
}

// One block = (chunk of 256 query points, batch b, direction dir).
// dir 0: query = preds, ref = gts   (loss_1: per-pred min over gts)
// dir 1: query = gts,   ref = preds (loss_2: per-gt  min over preds)
// Each thread: min over all ref points of (||r||^2 - 2 q.r), then + ||q||^2.
// Block-sums written to partials[dir][b][chunk] (deterministic, no atomics).
__global__ void __launch_bounds__(TPB) chamfer_dir(const float4* __restrict__ P4,
                                                   const float4* __restrict__ G4,
                                                   float* __restrict__ partials,
                                                   int N, int M, int B, int chunksMax) {
    const int dir   = blockIdx.z;
    const int b     = blockIdx.y;
    const int chunk = blockIdx.x;

    const float4* __restrict__ Q = (dir == 0) ? (P4 + (size_t)b * N) : (G4 + (size_t)b * M);
    const float4* __restrict__ R = (dir == 0) ? (G4 + (size_t)b * M) : (P4 + (size_t)b * N);
    const int nQ = (dir == 0) ? N : M;
    const int nR = (dir == 0) ? M : N;

    const int q = chunk * TPB + (int)threadIdx.x;
    float qx = 0.f, qy = 0.f, qz = 0.f, qw = 0.f;
    const bool valid = (q < nQ);
    if (valid) {
        float4 t = Q[q];
        qx = t.x; qy = t.y; qz = t.z; qw = t.w;
    }

    // 4 independent min accumulators to break the fminf dependency chain.
    float m0 = 3.4e38f, m1 = 3.4e38f, m2 = 3.4e38f, m3 = 3.4e38f;
    int i = 0;
    for (; i + 3 < nR; i += 4) {
        // Wave-uniform 16B loads (loop index is uniform) -> scalar/broadcast path.
        float4 r0 = R[i + 0];
        float4 r1 = R[i + 1];
        float4 r2 = R[i + 2];
        float4 r3 = R[i + 3];
        float d0 = fmaf(-2.f, fmaf(qx, r0.x, fmaf(qy, r0.y, qz * r0.z)), r0.w);
        float d1 = fmaf(-2.f, fmaf(qx, r1.x, fmaf(qy, r1.y, qz * r1.z)), r1.w);
        float d2 = fmaf(-2.f, fmaf(qx, r2.x, fmaf(qy, r2.y, qz * r2.z)), r2.w);
        float d3 = fmaf(-2.f, fmaf(qx, r3.x, fmaf(qy, r3.y, qz * r3.z)), r3.w);
        m0 = fminf(m0, d0);
        m1 = fminf(m1, d1);
        m2 = fminf(m2, d2);
        m3 = fminf(m3, d3);
    }
    for (; i < nR; ++i) {
        float4 r0 = R[i];
        float d0 = fmaf(-2.f, fmaf(qx, r0.x, fmaf(qy, r0.y, qz * r0.z)), r0.w);
        m0 = fminf(m0, d0);
    }
    float m = fminf(fminf(m0, m1), fminf(m2, m3)) + qw;
    if (!valid) m = 0.f;  // invalid lanes contribute zero to the sum

    // Deterministic block-sum: wave64 shuffle reduce, then LDS across 4 waves.
    for (int off = 32; off > 0; off >>= 1) m += __shfl_down(m, off);
    __shared__ float red[TPB / 64];
    const int wid  = (int)threadIdx.x >> 6;
    const int lane = (int)threadIdx.x & 63;
    if (lane == 0) red[wid] = m;
    __syncthreads();
    if (threadIdx.x == 0) {
        float s = 0.f;
        #pragma unroll
        for (int w = 0; w < TPB / 64; ++w) s += red[w];
        partials[((size_t)dir * B + b) * chunksMax + chunk] = s;
    }
}

__global__ void final_reduce(const float* __restrict__ partials, float* __restrict__ out,
                             int B, int chunksMax, int chunksN, int chunksM, int N, int M) {
    int b = (int)threadIdx.x;
    if (b < B) {
        float s0 = 0.f, s1 = 0.f;
        for (int c = 0; c < chunksN; ++c) s0 += partials[((size_t)0 * B + b) * chunksMax + c];
        for (int c = 0; c < chunksM; ++c) s1 += partials[((size_t)1 * B + b) * chunksMax + c];
        out[b] = s0 / (float)N + s1 / (float)M;  // loss_1 + loss_2
    }
}

extern "C" void kernel_launch(void* const* d_in, const int* in_sizes, int n_in,
                              void* d_out, int out_size, void* d_ws, size_t ws_size,
                              hipStream_t stream) {
    const float* preds = (const float*)d_in[0];  // [B, N, 3]
    const float* gts   = (const float*)d_in[1];  // [B, M, 3]
    float* out = (float*)d_out;                  // [B]

    const int B = out_size;                      // 8
    const int N = in_sizes[0] / (B * 3);         // 8192
    const int M = in_sizes[1] / (B * 3);         // 8192

    float4* P4 = (float4*)d_ws;                  // [B*N] packed preds
    float4* G4 = P4 + (size_t)B * N;             // [B*M] packed gts
    float*  partials = (float*)(G4 + (size_t)B * M);

    const int chunksN  = (N + TPB - 1) / TPB;
    const int chunksM  = (M + TPB - 1) / TPB;
    const int chunksMax = chunksN > chunksM ? chunksN : chunksM;

    const int totalP = B * N;
    const int totalG = B * M;
    pack_pts<<<(totalP + 255) / 256, 256, 0, stream>>>(preds, P4, totalP);
    pack_pts<<<(totalG + 255) / 256, 256, 0, stream>>>(gts, G4, totalG);

    dim3 grid(chunksMax, B, 2);
    chamfer_dir<<<grid, TPB, 0, stream>>>(P4, G4, partials, N, M, B, chunksMax);

    final_reduce<<<1, 64, 0, stream>>>(partials, out, B, chunksMax, chunksN, chunksM, N, M);
}

// Round 2
// 150.255 us; speedup vs baseline: 3.8962x; 3.8962x over previous
//
#include <hip/hip_runtime.h>

#define TPB 256
#define QPT 4    // queries per thread
#define NSEG 16  // ref-dimension split

// Pack [total][3] float points into float4 {x, y, z, x^2+y^2+z^2}.
__global__ void __launch_bounds__(256) pack_pts(const float* __restrict__ pts,
                                                float4* __restrict__ out, int total) {
    int i = blockIdx.x * blockDim.x + threadIdx.x;
    if (i < total) {
        float x = pts[3 * i + 0];
        float y = pts[3 * i + 1];
        float z = pts[3 * i + 2];
        out[i] = make_float4(x, y, z, fmaf(x, x, fmaf(y, y, z * z)));
    }
}

// Grid: (qChunks, NSEG, 2*B). Each thread owns QPT queries (strided by TPB for
// coalescing) and scans one segment of the ref points. Per-pair cost: 3 FMA +
// amortized min3. Partial per-query mins (with +||q||^2 folded in) are written
// to partials[db][seg][q]; invalid queries write 0.
__global__ void __launch_bounds__(TPB, 8) chamfer_dir(const float4* __restrict__ P4,
                                                      const float4* __restrict__ G4,
                                                      float* __restrict__ partials,
                                                      int N, int M, int B, int nQpad) {
    const int db  = blockIdx.z;          // dir*B + b
    const int dir = db / B;
    const int b   = db - dir * B;
    const int seg = blockIdx.y;

    const float4* __restrict__ Q = (dir == 0) ? (P4 + (size_t)b * N) : (G4 + (size_t)b * M);
    const float4* __restrict__ R = (dir == 0) ? (G4 + (size_t)b * M) : (P4 + (size_t)b * N);
    const int nQ = (dir == 0) ? N : M;
    const int nR = (dir == 0) ? M : N;

    const int segLen = (nR + NSEG - 1) / NSEG;
    const int s0 = seg * segLen;
    const int s1 = (s0 + segLen < nR) ? (s0 + segLen) : nR;

    const int qbase = blockIdx.x * (TPB * QPT) + (int)threadIdx.x;

    float q2x[QPT], q2y[QPT], q2z[QPT], qw[QPT], m[QPT];
    bool valid[QPT];
    #pragma unroll
    for (int j = 0; j < QPT; ++j) {
        const int q = qbase + j * TPB;
        valid[j] = (q < nQ);
        float4 t = valid[j] ? Q[q] : make_float4(0.f, 0.f, 0.f, 0.f);
        q2x[j] = -2.f * t.x;
        q2y[j] = -2.f * t.y;
        q2z[j] = -2.f * t.z;
        qw[j]  = t.w;
        m[j]   = 3.4e38f;
    }

    int i = s0;
    for (; i + 3 < s1; i += 4) {
        // Uniform addresses -> scalar loads (off the VALU pipe).
        float4 r0 = R[i + 0];
        float4 r1 = R[i + 1];
        float4 r2 = R[i + 2];
        float4 r3 = R[i + 3];
        #pragma unroll
        for (int j = 0; j < QPT; ++j) {
            float d0 = fmaf(q2x[j], r0.x, fmaf(q2y[j], r0.y, fmaf(q2z[j], r0.z, r0.w)));
            float d1 = fmaf(q2x[j], r1.x, fmaf(q2y[j], r1.y, fmaf(q2z[j], r1.z, r1.w)));
            float d2 = fmaf(q2x[j], r2.x, fmaf(q2y[j], r2.y, fmaf(q2z[j], r2.z, r2.w)));
            float d3 = fmaf(q2x[j], r3.x, fmaf(q2y[j], r3.y, fmaf(q2z[j], r3.z, r3.w)));
            m[j] = fminf(fminf(m[j], d0), d1);   // -> v_min3_f32
            m[j] = fminf(fminf(m[j], d2), d3);   // -> v_min3_f32
        }
    }
    for (; i < s1; ++i) {
        float4 r0 = R[i];
        #pragma unroll
        for (int j = 0; j < QPT; ++j) {
            float d0 = fmaf(q2x[j], r0.x, fmaf(q2y[j], r0.y, fmaf(q2z[j], r0.z, r0.w)));
            m[j] = fminf(m[j], d0);
        }
    }

    float* dst = partials + ((size_t)db * NSEG + seg) * nQpad;
    #pragma unroll
    for (int j = 0; j < QPT; ++j) {
        const int q = qbase + j * TPB;
        if (q < nQpad) dst[q] = valid[j] ? (m[j] + qw[j]) : 0.f;
    }
}

// One block per (dir,b): min across NSEG segments, sum across queries.
__global__ void __launch_bounds__(TPB) combine_dir(const float* __restrict__ partials,
                                                   float* __restrict__ sums,
                                                   int N, int M, int B, int nQpad) {
    const int db  = blockIdx.x;
    const int dir = db / B;
    const int nQ  = (dir == 0) ? N : M;

    const float* base = partials + (size_t)db * NSEG * nQpad;
    float sum = 0.f;
    for (int q = (int)threadIdx.x; q < nQ; q += TPB) {
        float v = base[q];
        #pragma unroll
        for (int s = 1; s < NSEG; ++s) v = fminf(v, base[(size_t)s * nQpad + q]);
        sum += v;
    }
    // Deterministic block-sum.
    for (int off = 32; off > 0; off >>= 1) sum += __shfl_down(sum, off);
    __shared__ float red[TPB / 64];
    const int wid  = (int)threadIdx.x >> 6;
    const int lane = (int)threadIdx.x & 63;
    if (lane == 0) red[wid] = sum;
    __syncthreads();
    if (threadIdx.x == 0) {
        float s = 0.f;
        #pragma unroll
        for (int w = 0; w < TPB / 64; ++w) s += red[w];
        sums[db] = s;
    }
}

__global__ void final_out(const float* __restrict__ sums, float* __restrict__ out,
                          int B, int N, int M) {
    int b = (int)threadIdx.x;
    if (b < B) out[b] = sums[b] / (float)N + sums[B + b] / (float)M;
}

extern "C" void kernel_launch(void* const* d_in, const int* in_sizes, int n_in,
                              void* d_out, int out_size, void* d_ws, size_t ws_size,
                              hipStream_t stream) {
    const float* preds = (const float*)d_in[0];  // [B, N, 3]
    const float* gts   = (const float*)d_in[1];  // [B, M, 3]
    float* out = (float*)d_out;                  // [B]

    const int B = out_size;                      // 8
    const int N = in_sizes[0] / (B * 3);         // 8192
    const int M = in_sizes[1] / (B * 3);         // 8192
    const int nQpad = (N > M ? N : M);

    float4* P4 = (float4*)d_ws;                  // [B*N]
    float4* G4 = P4 + (size_t)B * N;             // [B*M]
    float*  partials = (float*)(G4 + (size_t)B * M);   // [2*B][NSEG][nQpad]
    float*  sums = partials + (size_t)2 * B * NSEG * nQpad;  // [2*B]

    const int totalP = B * N;
    const int totalG = B * M;
    pack_pts<<<(totalP + 255) / 256, 256, 0, stream>>>(preds, P4, totalP);
    pack_pts<<<(totalG + 255) / 256, 256, 0, stream>>>(gts, G4, totalG);

    const int qChunks = (nQpad + TPB * QPT - 1) / (TPB * QPT);
    dim3 grid(qChunks, NSEG, 2 * B);
    chamfer_dir<<<grid, TPB, 0, stream>>>(P4, G4, partials, N, M, B, nQpad);

    combine_dir<<<2 * B, TPB, 0, stream>>>(partials, sums, N, M, B, nQpad);
    final_out<<<1, 64, 0, stream>>>(sums, out, B, N, M);
}

// Round 3
// 135.224 us; speedup vs baseline: 4.3293x; 1.1112x over previous
//
#include <hip/hip_runtime.h>

#define TPB 256
#define QPT 8    // queries per thread
#define NSEG 32  // ref-dimension split

// Order-preserving float<->uint encoding so atomicMin(uint) == float min.
__device__ __forceinline__ unsigned encf(float f) {
    unsigned u = __float_as_uint(f);
    return (u & 0x80000000u) ? ~u : (u | 0x80000000u);
}
__device__ __forceinline__ float decf(unsigned u) {
    return __uint_as_float((u & 0x80000000u) ? (u ^ 0x80000000u) : ~u);
}

// Pack [total][3] float points into float4 {x, y, z, x^2+y^2+z^2}.
__global__ void __launch_bounds__(256) pack_pts(const float* __restrict__ pts,
                                                float4* __restrict__ out, int total) {
    int i = blockIdx.x * blockDim.x + threadIdx.x;
    if (i < total) {
        float x = pts[3 * i + 0];
        float y = pts[3 * i + 1];
        float z = pts[3 * i + 2];
        out[i] = make_float4(x, y, z, fmaf(x, x, fmaf(y, y, z * z)));
    }
}

__global__ void __launch_bounds__(256) init_mins(unsigned* __restrict__ umins, int total) {
    int i = blockIdx.x * blockDim.x + threadIdx.x;
    if (i < total) umins[i] = 0xFFFFFFFFu;  // encodes "+max" — identity for min
}

// Grid: (qChunks, NSEG, 2*B). Each thread owns QPT queries (strided by TPB) and
// scans one ref segment with explicit register prefetch (scalar loads). Result
// per query: min over segment of (||r||^2 - 2 q.r) + ||q||^2, atomicMin'd into
// umins[db*nQpad + q] (order-independent -> deterministic).
__global__ void __launch_bounds__(TPB, 8) chamfer_dir(const float4* __restrict__ P4,
                                                      const float4* __restrict__ G4,
                                                      unsigned* __restrict__ umins,
                                                      int N, int M, int B, int nQpad) {
    const int db  = blockIdx.z;          // dir*B + b
    const int dir = db / B;
    const int b   = db - dir * B;
    const int seg = blockIdx.y;

    const float4* __restrict__ Q = (dir == 0) ? (P4 + (size_t)b * N) : (G4 + (size_t)b * M);
    const float4* __restrict__ R = (dir == 0) ? (G4 + (size_t)b * M) : (P4 + (size_t)b * N);
    const int nQ = (dir == 0) ? N : M;
    const int nR = (dir == 0) ? M : N;

    const int segLen = (nR + NSEG - 1) / NSEG;
    const int s0 = seg * segLen;
    const int s1 = (s0 + segLen < nR) ? (s0 + segLen) : nR;
    if (s0 >= s1) return;

    const int qbase = blockIdx.x * (TPB * QPT) + (int)threadIdx.x;

    float q2x[QPT], q2y[QPT], q2z[QPT], qw[QPT], m[QPT];
    #pragma unroll
    for (int j = 0; j < QPT; ++j) {
        const int q  = qbase + j * TPB;
        const int qc = (q < nQ) ? q : 0;   // clamp; guarded at the atomic
        float4 t = Q[qc];
        q2x[j] = -2.f * t.x;
        q2y[j] = -2.f * t.y;
        q2z[j] = -2.f * t.z;
        qw[j]  = t.w;
        m[j]   = 3.4e38f;
    }

#define PAIR(rr, jj)  fmaf(q2x[jj], (rr).x, fmaf(q2y[jj], (rr).y, fmaf(q2z[jj], (rr).z, (rr).w)))

    int i = s0;
    if (s1 - s0 >= 8) {
        float4 r0 = R[i + 0], r1 = R[i + 1], r2 = R[i + 2], r3 = R[i + 3];
        for (; i + 8 <= s1; i += 4) {
            // Prefetch next 64B (uniform -> scalar loads issue early).
            float4 n0 = R[i + 4], n1 = R[i + 5], n2 = R[i + 6], n3 = R[i + 7];
            #pragma unroll
            for (int j = 0; j < QPT; ++j) {
                float d0 = PAIR(r0, j);
                float d1 = PAIR(r1, j);
                float d2 = PAIR(r2, j);
                float d3 = PAIR(r3, j);
                m[j] = fminf(fminf(m[j], d0), d1);   // -> v_min3_f32
                m[j] = fminf(fminf(m[j], d2), d3);   // -> v_min3_f32
            }
            r0 = n0; r1 = n1; r2 = n2; r3 = n3;
        }
        #pragma unroll
        for (int j = 0; j < QPT; ++j) {
            float d0 = PAIR(r0, j);
            float d1 = PAIR(r1, j);
            float d2 = PAIR(r2, j);
            float d3 = PAIR(r3, j);
            m[j] = fminf(fminf(m[j], d0), d1);
            m[j] = fminf(fminf(m[j], d2), d3);
        }
        i += 4;
    }
    for (; i < s1; ++i) {
        float4 r = R[i];
        #pragma unroll
        for (int j = 0; j < QPT; ++j) m[j] = fminf(m[j], PAIR(r, j));
    }
#undef PAIR

    unsigned* dst = umins + (size_t)db * nQpad;
    #pragma unroll
    for (int j = 0; j < QPT; ++j) {
        const int q = qbase + j * TPB;
        if (q < nQ) atomicMin(&dst[q], encf(m[j] + qw[j]));
    }
}

// One block per batch b: sum decoded mins for both directions, write out[b].
__global__ void __launch_bounds__(TPB) finish(const unsigned* __restrict__ umins,
                                              float* __restrict__ out,
                                              int N, int M, int B, int nQpad) {
    const int b = blockIdx.x;
    const unsigned* m0 = umins + (size_t)b * nQpad;            // dir 0 (per-pred)
    const unsigned* m1 = umins + (size_t)(B + b) * nQpad;      // dir 1 (per-gt)

    float s0 = 0.f, s1 = 0.f;
    for (int q = (int)threadIdx.x; q < N; q += TPB) s0 += decf(m0[q]);
    for (int q = (int)threadIdx.x; q < M; q += TPB) s1 += decf(m1[q]);

    for (int off = 32; off > 0; off >>= 1) {
        s0 += __shfl_down(s0, off);
        s1 += __shfl_down(s1, off);
    }
    __shared__ float r0s[TPB / 64], r1s[TPB / 64];
    const int wid  = (int)threadIdx.x >> 6;
    const int lane = (int)threadIdx.x & 63;
    if (lane == 0) { r0s[wid] = s0; r1s[wid] = s1; }
    __syncthreads();
    if (threadIdx.x == 0) {
        float S0 = 0.f, S1 = 0.f;
        #pragma unroll
        for (int w = 0; w < TPB / 64; ++w) { S0 += r0s[w]; S1 += r1s[w]; }
        out[b] = S0 / (float)N + S1 / (float)M;
    }
}

extern "C" void kernel_launch(void* const* d_in, const int* in_sizes, int n_in,
                              void* d_out, int out_size, void* d_ws, size_t ws_size,
                              hipStream_t stream) {
    const float* preds = (const float*)d_in[0];  // [B, N, 3]
    const float* gts   = (const float*)d_in[1];  // [B, M, 3]
    float* out = (float*)d_out;                  // [B]

    const int B = out_size;                      // 8
    const int N = in_sizes[0] / (B * 3);         // 8192
    const int M = in_sizes[1] / (B * 3);         // 8192
    const int nQpad = (N > M ? N : M);

    float4*   P4    = (float4*)d_ws;             // [B*N]
    float4*   G4    = P4 + (size_t)B * N;        // [B*M]
    unsigned* umins = (unsigned*)(G4 + (size_t)B * M);  // [2*B][nQpad]

    const int totalP = B * N;
    const int totalG = B * M;
    const int totalU = 2 * B * nQpad;
    pack_pts<<<(totalP + 255) / 256, 256, 0, stream>>>(preds, P4, totalP);
    pack_pts<<<(totalG + 255) / 256, 256, 0, stream>>>(gts, G4, totalG);
    init_mins<<<(totalU + 255) / 256, 256, 0, stream>>>(umins, totalU);

    const int qChunks = (nQpad + TPB * QPT - 1) / (TPB * QPT);
    dim3 grid(qChunks, NSEG, 2 * B);
    chamfer_dir<<<grid, TPB, 0, stream>>>(P4, G4, umins, N, M, B, nQpad);

    finish<<<B, TPB, 0, stream>>>(umins, out, N, M, B, nQpad);
}